// Round 2
// baseline (187.443 us; speedup 1.0000x reference)
//
#include <hip/hip_runtime.h>

// ChamferLossSelf: B=4, N=4096, D=3, fp32 in/out. out = loss1 + loss2 + ordering.
constexpr int BATCH = 4;
constexpr int NPTS  = 4096;
constexpr int QC    = 512;   // queries per block
constexpr int TC    = 1024;  // targets per block (staged in LDS)
constexpr int NTHR  = 256;
constexpr int QPT   = QC / NTHR;  // 2 queries per thread

// ws layout: uint nnmin[4][BATCH][NPTS]  (float bits, atomicMin-able since >= 0)
// pass 0: query=gts,  target=preds  -> loss_2 terms (each gts point's NN among preds)
// pass 1: query=preds,target=gts    -> loss_1 terms (each pred point's NN among gts)
// pass 2: query=gts,  target=gts    (skip diag) -> mins1
// pass 3: query=preds,target=preds  (skip diag) -> mins2

__global__ __launch_bounds__(256) void nn_init(unsigned int* __restrict__ m) {
    int i = blockIdx.x * blockDim.x + threadIdx.x;
    m[i] = 0x7F800000u;  // +inf
}

__global__ __launch_bounds__(NTHR) void nn_pass(const float* __restrict__ gts,
                                                const float* __restrict__ preds,
                                                unsigned int* __restrict__ nnmin) {
    const int pass  = blockIdx.z & 3;
    const int b     = blockIdx.z >> 2;
    const int qbase = blockIdx.y * QC;
    const int tbase = blockIdx.x * TC;
    const bool selfp = (pass >= 2);
    const float* __restrict__ A = (pass == 0 || pass == 2) ? gts : preds;
    const float* __restrict__ T = (pass == 1 || pass == 2) ? gts : preds;

    __shared__ float4 tp[TC];  // 16 KB
    for (int k = threadIdx.x; k < TC; k += NTHR) {
        const float* p = T + ((size_t)b * NPTS + tbase + k) * 3;
        tp[k] = make_float4(p[0], p[1], p[2], 0.f);
    }
    __syncthreads();

    float qx[QPT], qy[QPT], qz[QPT], mn[QPT];
    int qidx[QPT];
#pragma unroll
    for (int q = 0; q < QPT; ++q) {
        const int qi = qbase + threadIdx.x + q * NTHR;
        qidx[q] = qi;
        const float* p = A + ((size_t)b * NPTS + qi) * 3;
        qx[q] = p[0]; qy[q] = p[1]; qz[q] = p[2];
        mn[q] = 1e30f;
    }

    if (selfp) {
#pragma unroll 4
        for (int j = 0; j < TC; ++j) {
            const float4 t = tp[j];
            const int tj = tbase + j;
#pragma unroll
            for (int q = 0; q < QPT; ++q) {
                const float dx = qx[q] - t.x, dy = qy[q] - t.y, dz = qz[q] - t.z;
                float d = dx * dx + dy * dy + dz * dz;
                d = (tj == qidx[q]) ? 1e30f : d;  // diag excluded (== 500000 fill semantics)
                mn[q] = fminf(mn[q], d);
            }
        }
    } else {
#pragma unroll 4
        for (int j = 0; j < TC; ++j) {
            const float4 t = tp[j];
#pragma unroll
            for (int q = 0; q < QPT; ++q) {
                const float dx = qx[q] - t.x, dy = qy[q] - t.y, dz = qz[q] - t.z;
                const float d = dx * dx + dy * dy + dz * dz;
                mn[q] = fminf(mn[q], d);
            }
        }
    }

    unsigned int* dst = nnmin + ((size_t)pass * BATCH + b) * NPTS;
#pragma unroll
    for (int q = 0; q < QPT; ++q)
        atomicMin(&dst[qidx[q]], __float_as_uint(mn[q]));
}

__global__ __launch_bounds__(512) void nn_finalize(const unsigned int* __restrict__ nnmin,
                                                   float* __restrict__ out) {
    const int b = blockIdx.x;
    const int tid = threadIdx.x;
    __shared__ float s1[NPTS];  // 16 KB
    __shared__ float s2[NPTS];  // 16 KB
    __shared__ float red[512];

    // cross-NN sums: loss_2 (pass 0) + loss_1 (pass 1)
    float acc = 0.f;
    const unsigned int* m0 = nnmin + ((size_t)0 * BATCH + b) * NPTS;
    const unsigned int* m1 = nnmin + ((size_t)1 * BATCH + b) * NPTS;
    for (int i = tid; i < NPTS; i += 512)
        acc += __uint_as_float(m0[i]) + __uint_as_float(m1[i]);

    // self-NN arrays -> LDS
    const unsigned int* m2 = nnmin + ((size_t)2 * BATCH + b) * NPTS;
    const unsigned int* m3 = nnmin + ((size_t)3 * BATCH + b) * NPTS;
    for (int i = tid; i < NPTS; i += 512) {
        s1[i] = __uint_as_float(m2[i]);
        s2[i] = __uint_as_float(m3[i]);
    }

    // bitonic sort both arrays ascending (sorted together to share barriers)
    for (int k = 2; k <= NPTS; k <<= 1) {
        for (int j = k >> 1; j > 0; j >>= 1) {
            __syncthreads();
            for (int t = tid; t < NPTS / 2; t += 512) {
                const int i = ((t & ~(j - 1)) << 1) | (t & (j - 1));
                const int p = i | j;
                const bool up = ((i & k) == 0);
                float a = s1[i], c = s1[p];
                if ((a > c) == up) { s1[i] = c; s1[p] = a; }
                float a2 = s2[i], c2 = s2[p];
                if ((a2 > c2) == up) { s2[i] = c2; s2[p] = a2; }
            }
        }
    }
    __syncthreads();

    float acco = 0.f;
    for (int i = tid; i < NPTS; i += 512) {
        const float d = s1[i] - s2[i];
        acco += d * d;
    }

    red[tid] = acc + acco;  // ALPHA = 1
    __syncthreads();
    for (int s = 256; s > 0; s >>= 1) {
        if (tid < s) red[tid] += red[tid + s];
        __syncthreads();
    }
    if (tid == 0) out[b] = red[0];
}

extern "C" void kernel_launch(void* const* d_in, const int* in_sizes, int n_in,
                              void* d_out, int out_size, void* d_ws, size_t ws_size,
                              hipStream_t stream) {
    const float* gts   = (const float*)d_in[0];
    const float* preds = (const float*)d_in[1];
    float* out = (float*)d_out;
    unsigned int* nnmin = (unsigned int*)d_ws;  // 4*BATCH*NPTS uints = 256 KB

    nn_init<<<(4 * BATCH * NPTS) / 256, 256, 0, stream>>>(nnmin);
    dim3 grid(NPTS / TC, NPTS / QC, BATCH * 4);  // (4, 8, 16) = 512 blocks
    nn_pass<<<grid, NTHR, 0, stream>>>(gts, preds, nnmin);
    nn_finalize<<<BATCH, 512, 0, stream>>>(nnmin, out);
}

// Round 4
// 132.861 us; speedup vs baseline: 1.4108x; 1.4108x over previous
//
#include <hip/hip_runtime.h>

// ChamferLossSelf: B=4, N=4096, D=3, fp32 in/out. out = loss1 + loss2 + ordering.
constexpr int BATCH = 4;
constexpr int NPTS  = 4096;
constexpr int QC    = 1024;  // queries per block
constexpr int TC    = 512;   // targets per block (staged in LDS)
constexpr int NTHR  = 256;
constexpr int QPT   = QC / NTHR;  // 4 queries per thread

// ws layout: uint nnmin[4][BATCH][NPTS]  (float bits, atomicMin-able since >= 0)
// pass 0: query=gts,  target=preds  -> loss_2 terms (per-gts NN among preds)
// pass 1: query=preds,target=gts    -> loss_1 terms (per-pred NN among gts)
// pass 2: query=gts,  target=gts    (diag excluded) -> mins1
// pass 3: query=preds,target=preds  (diag excluded) -> mins2
// nn_sort sorts pass-2/3 slots in place (ascending float values).

__global__ __launch_bounds__(256) void nn_init(unsigned int* __restrict__ m) {
    int i = blockIdx.x * blockDim.x + threadIdx.x;
    m[i] = 0x7F800000u;  // +inf
}

__global__ __launch_bounds__(NTHR) void nn_pass(const float* __restrict__ gts,
                                                const float* __restrict__ preds,
                                                unsigned int* __restrict__ nnmin) {
    const int pass  = blockIdx.z & 3;
    const int b     = blockIdx.z >> 2;
    const int qbase = blockIdx.y * QC;
    const int tbase = blockIdx.x * TC;
    const bool selfp = (pass >= 2);
    const float* __restrict__ A = (pass == 0 || pass == 2) ? gts : preds;
    const float* __restrict__ T = (pass == 1 || pass == 2) ? gts : preds;

    __shared__ float4 tp[TC];  // 8 KB
    for (int k = threadIdx.x; k < TC; k += NTHR) {
        const float* p = T + ((size_t)b * NPTS + tbase + k) * 3;
        tp[k] = make_float4(p[0], p[1], p[2], 0.f);
    }
    __syncthreads();

    float qx[QPT], qy[QPT], qz[QPT], mn[QPT];
    int qidx[QPT];
#pragma unroll
    for (int q = 0; q < QPT; ++q) {
        const int qi = qbase + threadIdx.x + q * NTHR;
        qidx[q] = qi;
        const float* p = A + ((size_t)b * NPTS + qi) * 3;
        qx[q] = p[0]; qy[q] = p[1]; qz[q] = p[2];
        mn[q] = 1e30f;
    }

    if (selfp) {
#pragma unroll 4
        for (int j = 0; j < TC; ++j) {
            const float4 t = tp[j];
            const int tj = tbase + j;
#pragma unroll
            for (int q = 0; q < QPT; ++q) {
                const float dx = qx[q] - t.x, dy = qy[q] - t.y, dz = qz[q] - t.z;
                float d = dx * dx;
                d = fmaf(dy, dy, d);
                d = fmaf(dz, dz, d);
                d = (tj == qidx[q]) ? 1e30f : d;  // diag excluded (== 500000 fill semantics)
                mn[q] = fminf(mn[q], d);
            }
        }
    } else {
#pragma unroll 4
        for (int j = 0; j < TC; ++j) {
            const float4 t = tp[j];
#pragma unroll
            for (int q = 0; q < QPT; ++q) {
                const float dx = qx[q] - t.x, dy = qy[q] - t.y, dz = qz[q] - t.z;
                float d = dx * dx;
                d = fmaf(dy, dy, d);
                d = fmaf(dz, dz, d);
                mn[q] = fminf(mn[q], d);
            }
        }
    }

    unsigned int* dst = nnmin + ((size_t)pass * BATCH + b) * NPTS;
#pragma unroll
    for (int q = 0; q < QPT; ++q)
        atomicMin(&dst[qidx[q]], __float_as_uint(mn[q]));
}

// One block per (batch, which) = 8 blocks; bitonic-sort 4096 floats in LDS, in place.
__global__ __launch_bounds__(1024) void nn_sort(unsigned int* __restrict__ nnmin) {
    const int which = blockIdx.x & 1;
    const int b     = blockIdx.x >> 1;
    unsigned int* src = nnmin + ((size_t)(2 + which) * BATCH + b) * NPTS;
    __shared__ float s[NPTS];  // 16 KB
    for (int i = threadIdx.x; i < NPTS; i += 1024) s[i] = __uint_as_float(src[i]);

    for (int k = 2; k <= NPTS; k <<= 1) {
        for (int j = k >> 1; j > 0; j >>= 1) {
            __syncthreads();
#pragma unroll
            for (int t = threadIdx.x; t < NPTS / 2; t += 1024) {
                const int i = ((t & ~(j - 1)) << 1) | (t & (j - 1));
                const int p = i | j;
                const bool up = ((i & k) == 0);
                const float a = s[i], c = s[p];
                if ((a > c) == up) { s[i] = c; s[p] = a; }
            }
        }
    }
    __syncthreads();
    for (int i = threadIdx.x; i < NPTS; i += 1024) src[i] = __float_as_uint(s[i]);
}

__global__ __launch_bounds__(512) void nn_reduce(const unsigned int* __restrict__ nnmin,
                                                 float* __restrict__ out) {
    const int b = blockIdx.x;
    const int tid = threadIdx.x;
    __shared__ float red[512];

    const unsigned int* m0 = nnmin + ((size_t)0 * BATCH + b) * NPTS;
    const unsigned int* m1 = nnmin + ((size_t)1 * BATCH + b) * NPTS;
    const unsigned int* s1 = nnmin + ((size_t)2 * BATCH + b) * NPTS;  // sorted
    const unsigned int* s2 = nnmin + ((size_t)3 * BATCH + b) * NPTS;  // sorted

    float acc = 0.f;
    for (int i = tid; i < NPTS; i += 512) {
        acc += __uint_as_float(m0[i]) + __uint_as_float(m1[i]);
        const float d = __uint_as_float(s1[i]) - __uint_as_float(s2[i]);
        acc = fmaf(d, d, acc);  // ALPHA = 1
    }

    red[tid] = acc;
    __syncthreads();
    for (int s = 256; s > 0; s >>= 1) {
        if (tid < s) red[tid] += red[tid + s];
        __syncthreads();
    }
    if (tid == 0) out[b] = red[0];
}

extern "C" void kernel_launch(void* const* d_in, const int* in_sizes, int n_in,
                              void* d_out, int out_size, void* d_ws, size_t ws_size,
                              hipStream_t stream) {
    const float* gts   = (const float*)d_in[0];
    const float* preds = (const float*)d_in[1];
    float* out = (float*)d_out;
    unsigned int* nnmin = (unsigned int*)d_ws;  // 4*BATCH*NPTS uints = 256 KB

    nn_init<<<(4 * BATCH * NPTS) / 256, 256, 0, stream>>>(nnmin);
    dim3 grid(NPTS / TC, NPTS / QC, BATCH * 4);  // (8, 4, 16) = 512 blocks
    nn_pass<<<grid, NTHR, 0, stream>>>(gts, preds, nnmin);
    nn_sort<<<2 * BATCH, 1024, 0, stream>>>(nnmin);
    nn_reduce<<<BATCH, 512, 0, stream>>>(nnmin, out);
}

// Round 5
// 125.914 us; speedup vs baseline: 1.4887x; 1.0552x over previous
//
#include <hip/hip_runtime.h>

// ChamferLossSelf: B=4, N=4096, D=3, fp32 in/out. out = loss1 + loss2 + ALPHA*ordering.
constexpr int BATCH = 4;
constexpr int NPTS  = 4096;
constexpr int TILE  = 128;
constexpr int NT    = NPTS / TILE;              // 32 tile-stripes
constexpr int CROSS_TILES = NT * NT;            // 1024
constexpr int TRI_TILES   = NT * (NT + 1) / 2;  // 528 (upper triangle incl. diag)
constexpr int TILES_PER_BATCH = CROSS_TILES + 2 * TRI_TILES;  // 2080

// ws layout: uint nnmin[4][BATCH][NPTS] (float bits; atomicMin valid since >= 0)
// slot 0: per-gts NN among preds (cross row-mins)  -> loss_2
// slot 1: per-pred NN among gts  (cross col-mins)  -> loss_1
// slot 2: per-gts self-NN (diag excluded)          -> mins1 (sorted in place)
// slot 3: per-pred self-NN (diag excluded)         -> mins2 (sorted in place)

__global__ __launch_bounds__(256) void nn_init(unsigned int* __restrict__ m) {
    int i = blockIdx.x * blockDim.x + threadIdx.x;
    m[i] = 0x7F800000u;  // +inf
}

__global__ __launch_bounds__(256) void nn_pass(const float* __restrict__ gts,
                                               const float* __restrict__ preds,
                                               unsigned int* __restrict__ nnmin) {
    const int b = blockIdx.y;
    int id = blockIdx.x;
    const float* A; const float* Bp;
    unsigned int* rowslot; unsigned int* colslot;
    int I, J;
    bool self;
    if (id < CROSS_TILES) {
        A = gts; Bp = preds;
        I = id >> 5; J = id & 31;
        rowslot = nnmin + ((size_t)0 * BATCH + b) * NPTS;
        colslot = nnmin + ((size_t)1 * BATCH + b) * NPTS;
        self = false;
    } else {
        id -= CROSS_TILES;
        const int which = id / TRI_TILES;  // 0: gts self, 1: preds self
        int t = id - which * TRI_TILES;
        int i = 0;
        while (t >= NT - i) { t -= NT - i; ++i; }  // triangle unrank (uniform, <=32 iters)
        I = i; J = i + t;
        A = which ? preds : gts; Bp = A;
        rowslot = colslot = nnmin + ((size_t)(2 + which) * BATCH + b) * NPTS;
        self = true;
    }

    __shared__ float4 arow[TILE];        // 2 KB
    __shared__ float4 bcol[TILE];        // 2 KB
    __shared__ float  rp[TILE][17];      // 8.5 KB (+1 pad: conflict-free reduce reads)
    __shared__ float  cp[TILE][17];      // 8.5 KB

    const int tid = threadIdx.x;
    if (tid < TILE) {
        const float* p = A + ((size_t)b * NPTS + I * TILE + tid) * 3;
        arow[tid] = make_float4(p[0], p[1], p[2], 0.f);
    } else {
        const float* p = Bp + ((size_t)b * NPTS + J * TILE + (tid - TILE)) * 3;
        bcol[tid - TILE] = make_float4(p[0], p[1], p[2], 0.f);
    }
    __syncthreads();

    const int tx = tid & 15, ty = tid >> 4;  // thread owns rows ty*8..+7, cols tx*8..+7
    float ax[8], ay[8], az[8], bx[8], by[8], bz[8];
#pragma unroll
    for (int r = 0; r < 8; ++r) {
        const float4 t = arow[ty * 8 + r];
        ax[r] = t.x; ay[r] = t.y; az[r] = t.z;
    }
#pragma unroll
    for (int c = 0; c < 8; ++c) {
        const float4 t = bcol[tx * 8 + c];
        bx[c] = t.x; by[c] = t.y; bz[c] = t.z;
    }

    float rmin[8], cmin[8];
#pragma unroll
    for (int r = 0; r < 8; ++r) { rmin[r] = 1e30f; cmin[r] = 1e30f; }

    // diag pairs exist only on self tiles with I==J and ty==tx, at r==c
    const bool dt = self && (I == J) && (ty == tx);

#pragma unroll
    for (int r = 0; r < 8; ++r) {
#pragma unroll
        for (int c = 0; c < 8; ++c) {
            const float dx = ax[r] - bx[c];
            const float dy = ay[r] - by[c];
            const float dz = az[r] - bz[c];
            float d = fmaf(dz, dz, fmaf(dy, dy, dx * dx));
            if (r == c) d = dt ? 1e30f : d;  // compile-time r==c: cndmask on 8/64 pairs
            rmin[r] = fminf(rmin[r], d);
            cmin[c] = fminf(cmin[c], d);
        }
    }

#pragma unroll
    for (int r = 0; r < 8; ++r) rp[ty * 8 + r][tx] = rmin[r];
#pragma unroll
    for (int c = 0; c < 8; ++c) cp[tx * 8 + c][ty] = cmin[c];
    __syncthreads();

    if (tid < TILE) {
        float m = rp[tid][0];
#pragma unroll
        for (int i = 1; i < 16; ++i) m = fminf(m, rp[tid][i]);
        atomicMin(&rowslot[I * TILE + tid], __float_as_uint(m));
    } else {
        const int t2 = tid - TILE;
        float m = cp[t2][0];
#pragma unroll
        for (int i = 1; i < 16; ++i) m = fminf(m, cp[t2][i]);
        atomicMin(&colslot[J * TILE + t2], __float_as_uint(m));
    }
}

// 8 blocks (batch x which). Bitonic sort 4096 floats: 4 elems/thread in registers;
// j<=2 in-thread, j in [4,128] via shfl_xor (no barriers), j>=256 via LDS.
__global__ __launch_bounds__(1024) void nn_sort(unsigned int* __restrict__ nnmin) {
    const int which = blockIdx.x & 1;
    const int b = blockIdx.x >> 1;
    unsigned int* src = nnmin + ((size_t)(2 + which) * BATCH + b) * NPTS;
    __shared__ float s[NPTS];  // 16 KB
    const int tid = threadIdx.x;
    const int base = tid * 4;

    const uint4 u = reinterpret_cast<const uint4*>(src)[tid];
    float v[4] = {__uint_as_float(u.x), __uint_as_float(u.y),
                  __uint_as_float(u.z), __uint_as_float(u.w)};

    for (int k = 2; k <= NPTS; k <<= 1) {
        if (k >= 512) {
            // element ownership is slot-local: each thread writes/reads only its own 4 slots
            s[base + 0] = v[0]; s[base + 1] = v[1]; s[base + 2] = v[2]; s[base + 3] = v[3];
            __syncthreads();
            for (int j = k >> 1; j >= 256; j >>= 1) {
#pragma unroll
                for (int tt = 0; tt < 2; ++tt) {
                    const int t = tid + tt * 1024;
                    const int i = ((t & ~(j - 1)) << 1) | (t & (j - 1));
                    const int p = i | j;
                    const bool asc = ((i & k) == 0);
                    const float a = s[i], c = s[p];
                    const float lo = fminf(a, c), hi = fmaxf(a, c);
                    s[i] = asc ? lo : hi;
                    s[p] = asc ? hi : lo;
                }
                __syncthreads();
            }
            v[0] = s[base + 0]; v[1] = s[base + 1]; v[2] = s[base + 2]; v[3] = s[base + 3];
        }
        // shuffle steps: j = min(k/2,128) .. 4 (partner lane = lane ^ (j/4), same elem)
        for (int j = (k >> 1) > 128 ? 128 : (k >> 1); j >= 4; j >>= 1) {
            const int m = j >> 2;
#pragma unroll
            for (int e = 0; e < 4; ++e) {
                const float p = __shfl_xor(v[e], m, 64);
                const int i = base + e;
                const bool keepmin = (((i & j) == 0) == ((i & k) == 0));
                v[e] = keepmin ? fminf(v[e], p) : fmaxf(v[e], p);
            }
        }
        if (k >= 4) {  // j = 2: pairs (0,2),(1,3); direction uniform within thread for k>=4
            const bool asc2 = ((base & k) == 0);
            float lo = fminf(v[0], v[2]), hi = fmaxf(v[0], v[2]);
            v[0] = asc2 ? lo : hi; v[2] = asc2 ? hi : lo;
            lo = fminf(v[1], v[3]); hi = fmaxf(v[1], v[3]);
            v[1] = asc2 ? lo : hi; v[3] = asc2 ? hi : lo;
        }
        {  // j = 1: pairs (0,1),(2,3)
            const bool ascA = (((base + 0) & k) == 0);
            const bool ascB = (((base + 2) & k) == 0);
            float lo = fminf(v[0], v[1]), hi = fmaxf(v[0], v[1]);
            v[0] = ascA ? lo : hi; v[1] = ascA ? hi : lo;
            lo = fminf(v[2], v[3]); hi = fmaxf(v[2], v[3]);
            v[2] = ascB ? lo : hi; v[3] = ascB ? hi : lo;
        }
    }

    reinterpret_cast<uint4*>(src)[tid] =
        make_uint4(__float_as_uint(v[0]), __float_as_uint(v[1]),
                   __float_as_uint(v[2]), __float_as_uint(v[3]));
}

__global__ __launch_bounds__(512) void nn_reduce(const unsigned int* __restrict__ nnmin,
                                                 float* __restrict__ out) {
    const int b = blockIdx.x;
    const int tid = threadIdx.x;
    __shared__ float red[512];

    const unsigned int* m0 = nnmin + ((size_t)0 * BATCH + b) * NPTS;
    const unsigned int* m1 = nnmin + ((size_t)1 * BATCH + b) * NPTS;
    const unsigned int* s1 = nnmin + ((size_t)2 * BATCH + b) * NPTS;  // sorted asc
    const unsigned int* s2 = nnmin + ((size_t)3 * BATCH + b) * NPTS;  // sorted asc

    float acc = 0.f;
    for (int i = tid; i < NPTS; i += 512) {
        acc += __uint_as_float(m0[i]) + __uint_as_float(m1[i]);
        const float d = __uint_as_float(s1[i]) - __uint_as_float(s2[i]);
        acc = fmaf(d, d, acc);  // ALPHA = 1
    }

    red[tid] = acc;
    __syncthreads();
    for (int s = 256; s > 0; s >>= 1) {
        if (tid < s) red[tid] += red[tid + s];
        __syncthreads();
    }
    if (tid == 0) out[b] = red[0];
}

extern "C" void kernel_launch(void* const* d_in, const int* in_sizes, int n_in,
                              void* d_out, int out_size, void* d_ws, size_t ws_size,
                              hipStream_t stream) {
    const float* gts   = (const float*)d_in[0];
    const float* preds = (const float*)d_in[1];
    float* out = (float*)d_out;
    unsigned int* nnmin = (unsigned int*)d_ws;  // 4*BATCH*NPTS uints = 256 KB

    nn_init<<<(4 * BATCH * NPTS) / 256, 256, 0, stream>>>(nnmin);
    dim3 grid(TILES_PER_BATCH, BATCH);  // 2080 x 4 = 8320 tile-blocks
    nn_pass<<<grid, 256, 0, stream>>>(gts, preds, nnmin);
    nn_sort<<<2 * BATCH, 1024, 0, stream>>>(nnmin);
    nn_reduce<<<BATCH, 512, 0, stream>>>(nnmin, out);
}